// Round 4
// baseline (479.872 us; speedup 1.0000x reference)
//
#include <hip/hip_runtime.h>

// VanillaVectorQuantizer: N=131072 positions (B=32,H=64,W=64), D=64, K=512.
// enc layout [B, D, H, W]: element (b,d,p) at b*D*HW + d*HW + p, p=h*64+w.
//
// Numerics are an EXACT emulation of the numpy fp32 reference chain
// (verified bitwise in rounds 2-3, absmax == 0):
//   - M_k: ascending-d fp32 FMA chain (== BLAS sgemm microkernel)
//   - sq_x: numpy pairwise_sum(n=64): 8 stride-8 accumulators of pre-rounded
//     squares (mul then add, NO fma), combine ((r0+r1)+(r2+r3))+((r4+r5)+(r6+r7))
//   - sq_e: sequential d-sum of pre-rounded squares (NO fma)
//   - dist: fl(fl(sq_x - fl(2*M)) + sq_e), contraction off
//   - strict '<' ascending k == np.argmin first-index tie-break
// DO NOT alter any of these chains. (x passing through LDS is bitwise-exact.)
//
// Perf history: r2 (x re-fetched from global each K-tile): 202us, VALU 61%.
// r3 (asm-pinned x -> scratch SPILL, VGPR=60): 477us, VALU 28%. Fix: x lives
// in LDS (xs[128][68], pad->full-BW b128 row reads); K-loop re-reads from the
// LDS pipe, regalloc needs only ~45 VGPRs. Wave-level K-split retained:
// waves 0-1 scan k[0,256), waves 2-3 k[256,512) (kbase wave-uniform -> cb/sqe
// stay scalar loads); LDS combine, ties -> lower half = np.argmin order.

#pragma clang fp contract(off)

#define VQ_D 64
#define VQ_K 512
#define VQ_HW 4096
#define VQ_N 131072
#define XS_STRIDE 68  // 64 + 4 pad: b128 reads start at bank 4*p -> 32 banks tiled

__global__ void vq_sqe_kernel(const float* __restrict__ cb,
                              float* __restrict__ sqe) {
    const int k = threadIdx.x;  // 512 threads, one block
    float s = cb[k] * cb[k];    // d = 0 (square rounded, then added: no fma)
    for (int d = 1; d < VQ_D; ++d) {
        const float v = cb[d * VQ_K + k];
        const float sq = v * v;  // contract(off): rounds the square
        s = s + sq;              // then rounds the add (numpy axis-0 reduce)
    }
    sqe[k] = s;
}

__global__ __launch_bounds__(256) void vq_main_kernel(
    const float* __restrict__ enc, const float* __restrict__ cb,
    const float* __restrict__ sqe, float* __restrict__ out) {
    __shared__ float xs[128 * XS_STRIDE];  // 34816 B
    __shared__ float sbest[256];
    __shared__ int sbk[256];

    const int tid = threadIdx.x;
    const int wid = tid >> 6;          // 0..3
    const int lane = tid & 63;
    const int half = wid >> 1;         // 0: k in [0,256), 1: k in [256,512)
    const int pidx = ((wid & 1) << 6) | lane;  // 0..127 within block
    const int pos0 = blockIdx.x * 128;
    const int b = pos0 >> 12;          // block is within one b (128 | 4096)
    const int r0 = pos0 & (VQ_HW - 1);
    const float* ebase = enc + (size_t)b * (VQ_D * VQ_HW) + r0;

    // Stage x into LDS: xs[p][d]. Global side: lanes p-consecutive -> 512B
    // segments. LDS side: 8-way bank alias on writes (one-time, negligible).
    {
        const int p_s = tid & 127;
        const int dbase = (tid >> 7) << 5;  // threads 0-127: d 0..31; 128-255: 32..63
        for (int i = 0; i < 32; ++i) {
            const int d = dbase + i;
            xs[p_s * XS_STRIDE + d] = ebase[(size_t)d * VQ_HW + p_s];
        }
    }
    __syncthreads();

    const float* xp = &xs[pidx * XS_STRIDE];

    // sq_x: exact emulation of numpy pairwise_sum over fl(x*x), n=64.
    float pr[8];
#pragma unroll
    for (int j = 0; j < 8; ++j) pr[j] = xp[j] * xp[j];
#pragma unroll
    for (int i = 8; i < VQ_D; i += 8) {
#pragma unroll
        for (int j = 0; j < 8; ++j) {
            const float sq = xp[i + j] * xp[i + j];  // rounded square
            pr[j] = pr[j] + sq;                      // rounded add
        }
    }
    const float sqx = ((pr[0] + pr[1]) + (pr[2] + pr[3])) +
                      ((pr[4] + pr[5]) + (pr[6] + pr[7]));

    float best = 3.402823466e38f;
    int bestk = 0;
    const int kbase = half << 8;  // wave-uniform -> cb/sqe stay scalar loads

    for (int kt = kbase; kt < kbase + 256; kt += 16) {
        float acc[16];
#pragma unroll
        for (int j = 0; j < 16; ++j) acc[j] = 0.f;
        // d in groups of 4: one ds_read_b128 of this thread's x row feeds
        // 64 FMAs; cb index is uniform -> s_load_dwordx16 per d.
#pragma unroll
        for (int d0 = 0; d0 < VQ_D; d0 += 4) {
            float xv[4];
#pragma unroll
            for (int dd = 0; dd < 4; ++dd) xv[dd] = xp[d0 + dd];
#pragma unroll
            for (int dd = 0; dd < 4; ++dd) {
#pragma unroll
                for (int j = 0; j < 16; ++j)  // ascending-d FMA chain == sgemm
                    acc[j] = fmaf(xv[dd], cb[(d0 + dd) * VQ_K + kt + j], acc[j]);
            }
        }
#pragma unroll
        for (int j = 0; j < 16; ++j) {
            const float m2 = 2.0f * acc[j];        // exact (power of 2)
            const float tmp = sqx - m2;            // rounds: fl(sq_x - 2M)
            const float dist = tmp + sqe[kt + j];  // rounds: + sq_e
            if (dist < best) {  // strict '<': first (lowest) index on ties
                best = dist;
                bestk = kt + j;
            }
        }
    }

    // Combine the two k-halves (disjoint ranges; strict '<' with half-0 as
    // base -> ties resolve to the lower k-range = np.argmin semantics).
    sbest[tid] = best;
    sbk[tid] = bestk;
    __syncthreads();
    if (half == 0) {
        const float ob = sbest[128 + pidx];
        if (ob < best) {
            best = ob;
            bestk = sbk[128 + pidx];
        }
        sbk[pidx] = bestk;  // publish final index for the half-1 partner
    }
    __syncthreads();
    bestk = sbk[pidx];

    // Gather winning codebook column; each half stores 32 of the 64 d-planes
    // (stores stay 256B-contiguous per wave: 64 consecutive positions).
    float* op = out + (size_t)b * (VQ_D * VQ_HW) + r0 + pidx;
    const int dbase = half << 5;
#pragma unroll
    for (int sd = 0; sd < 32; ++sd) {
        const int d = dbase + sd;
        op[(size_t)d * VQ_HW] = cb[d * VQ_K + bestk];
    }
}

extern "C" void kernel_launch(void* const* d_in, const int* in_sizes, int n_in,
                              void* d_out, int out_size, void* d_ws, size_t ws_size,
                              hipStream_t stream) {
    const float* enc = (const float*)d_in[0];  // [32,64,64,64]
    const float* cb  = (const float*)d_in[1];  // [64,512]
    float* out = (float*)d_out;
    float* sqe = (float*)d_ws;  // 512 floats

    vq_sqe_kernel<<<1, VQ_K, 0, stream>>>(cb, sqe);
    vq_main_kernel<<<VQ_N / 128, 256, 0, stream>>>(enc, cb, sqe, out);
}

// Round 5
// 202.863 us; speedup vs baseline: 2.3655x; 2.3655x over previous
//
#include <hip/hip_runtime.h>

// VanillaVectorQuantizer: N=131072 positions (B=32,H=64,W=64), D=64, K=512.
// enc layout [B, D, H, W]: element (b,d,p) at b*D*HW + d*HW + p, p=h*64+w.
//
// Numerics are an EXACT emulation of the numpy fp32 reference chain
// (verified bitwise in rounds 2-4, absmax == 0):
//   - M_k: ascending-d fp32 FMA chain (== BLAS sgemm microkernel)
//   - sq_x: numpy pairwise_sum(n=64): 8 stride-8 accumulators of pre-rounded
//     squares (mul then add, NO fma), combine ((r0+r1)+(r2+r3))+((r4+r5)+(r6+r7))
//   - sq_e: sequential d-sum of pre-rounded squares (NO fma)
//   - dist: fl(fl(sq_x - fl(2*M)) + sq_e), contraction off
//   - strict '<' ascending k == np.argmin first-index tie-break
// DO NOT alter any of these chains.
//
// Perf history:
//   r2: thread=position, loop-uniform kt (cb via s_load_dwordx16): 202us,
//       VALU 61%, but VGPR=48 -> compiler SANK x[64] into per-tile global
//       reloads (default launch_bounds targets occupancy we can't use:
//       grid=512 blocks is 2 blocks/CU regardless).
//   r3: asm-pinned x -> scratch spill: 477us, VALU 28%.
//   r4: kbase=(tid>>7)<<8 K-split de-uniformized the cb index -> LLVM
//       divergence analysis demoted cb/sqe to per-lane VECTOR loads: 480us.
// Fix: r2 structure (kt loop-uniform -> provably scalar cb) +
// __launch_bounds__(256, 2): declare the 2-waves/SIMD occupancy we actually
// have -> 256-VGPR budget -> x[64] stays register-resident, no sinking.

#pragma clang fp contract(off)

#define VQ_D 64
#define VQ_K 512
#define VQ_HW 4096
#define VQ_N 131072

__global__ void vq_sqe_kernel(const float* __restrict__ cb,
                              float* __restrict__ sqe) {
    const int k = threadIdx.x;  // 512 threads, one block
    float s = cb[k] * cb[k];    // d = 0 (square rounded, then added: no fma)
    for (int d = 1; d < VQ_D; ++d) {
        const float v = cb[d * VQ_K + k];
        const float sq = v * v;  // contract(off): rounds the square
        s = s + sq;              // then rounds the add (numpy axis-0 reduce)
    }
    sqe[k] = s;
}

__global__ __launch_bounds__(256, 2) void vq_main_kernel(
    const float* __restrict__ enc, const float* __restrict__ cb,
    const float* __restrict__ sqe, float* __restrict__ out) {
    const int t = blockIdx.x * 256 + threadIdx.x;  // position id
    if (t >= VQ_N) return;
    const int b = t >> 12;            // position / (H*W)
    const int r = t & (VQ_HW - 1);    // h*64+w
    const float* xp = enc + (size_t)b * (VQ_D * VQ_HW) + r;

    // Load this position's vector into registers (coalesced across lanes).
    // With waves-per-EU=2 the VGPR budget is 256: these 64 values stay
    // register-resident across the K-loop (no sinking, no spilling).
    float x[VQ_D];
#pragma unroll
    for (int d = 0; d < VQ_D; ++d) x[d] = xp[(size_t)d * VQ_HW];

    // sq_x: exact emulation of numpy pairwise_sum over fl(x*x), n=64.
    float pr[8];
#pragma unroll
    for (int j = 0; j < 8; ++j) pr[j] = x[j] * x[j];
#pragma unroll
    for (int i = 8; i < VQ_D; i += 8) {
#pragma unroll
        for (int j = 0; j < 8; ++j) {
            const float sq = x[i + j] * x[i + j];  // rounded square
            pr[j] = pr[j] + sq;                    // rounded add
        }
    }
    const float sqx = ((pr[0] + pr[1]) + (pr[2] + pr[3])) +
                      ((pr[4] + pr[5]) + (pr[6] + pr[7]));

    float best = 3.402823466e38f;
    int bestk = 0;

    // K tiled by 16; kt is loop-uniform (NOT thread-derived) so cb/sqe
    // indices are provably uniform -> s_load_dwordx16 scalar path.
    for (int kt = 0; kt < VQ_K; kt += 16) {
        float acc[16];
#pragma unroll
        for (int j = 0; j < 16; ++j) acc[j] = 0.f;
#pragma unroll
        for (int d = 0; d < VQ_D; ++d) {
            const float xd = x[d];
#pragma unroll
            for (int j = 0; j < 16; ++j)  // ascending-d FMA chain == sgemm
                acc[j] = fmaf(xd, cb[d * VQ_K + kt + j], acc[j]);
        }
#pragma unroll
        for (int j = 0; j < 16; ++j) {
            const float m2 = 2.0f * acc[j];        // exact (power of 2)
            const float tmp = sqx - m2;            // rounds: fl(sq_x - 2M)
            const float dist = tmp + sqe[kt + j];  // rounds: + sq_e
            if (dist < best) {  // strict '<': first (lowest) index on ties
                best = dist;
                bestk = kt + j;
            }
        }
    }

    // Gather winning codebook column, store strided (coalesced across lanes).
    float* op = out + (size_t)b * (VQ_D * VQ_HW) + r;
#pragma unroll
    for (int d = 0; d < VQ_D; ++d) op[(size_t)d * VQ_HW] = cb[d * VQ_K + bestk];
}

extern "C" void kernel_launch(void* const* d_in, const int* in_sizes, int n_in,
                              void* d_out, int out_size, void* d_ws, size_t ws_size,
                              hipStream_t stream) {
    const float* enc = (const float*)d_in[0];  // [32,64,64,64]
    const float* cb  = (const float*)d_in[1];  // [64,512]
    float* out = (float*)d_out;
    float* sqe = (float*)d_ws;  // 512 floats

    vq_sqe_kernel<<<1, VQ_K, 0, stream>>>(cb, sqe);
    vq_main_kernel<<<VQ_N / 256, 256, 0, stream>>>(enc, cb, sqe, out);
}

// Round 6
// 198.681 us; speedup vs baseline: 2.4153x; 1.0210x over previous
//
#include <hip/hip_runtime.h>

// VanillaVectorQuantizer: N=131072 positions (B=32,H=64,W=64), D=64, K=512.
// enc layout [B, D, H, W]: element (b,d,p) at b*D*HW + d*HW + p, p=h*64+w.
//
// Numerics are an EXACT emulation of the numpy fp32 reference chain
// (verified bitwise in rounds 2-5, absmax == 0):
//   - M_k: ascending-d fp32 FMA chain (== BLAS sgemm microkernel)
//   - sq_x: numpy pairwise_sum(n=64): 8 stride-8 accumulators of pre-rounded
//     squares (mul then add, NO fma), combine ((r0+r1)+(r2+r3))+((r4+r5)+(r6+r7))
//   - sq_e: sequential d-sum of pre-rounded squares (NO fma)
//   - dist: fl(fl(sq_x - fl(2*M)) + sq_e), contraction off
//   - strict '<' ascending k == np.argmin first-index tie-break
// DO NOT alter any of these chains. (x through LDS is bitwise-exact.)
//
// Perf history:
//   r2/r5: thread=position, uniform kt (scalar cb), x in "registers": 202us,
//          VALU 60%, VGPR=48 -> backend SINKS x loads into the K-loop
//          (32x global re-fetch). launch_bounds(256,2) changed nothing:
//          sinking is not occupancy-budget-driven. Stop fighting regalloc.
//   r3:    asm-pinned x -> scratch spill: 477us.
//   r4:    LDS-x BUT tid-derived kbase de-uniformized the cb index ->
//          per-lane vector loads of cb dominated: 480us. LDS-x itself
//          was never the problem.
// This round: uniform kt (scalar cb, proven) x LDS-resident x (proven
// staging). Reloads from LDS are structurally cheap (16 ds_read_b128/tile,
// hidden under 2048 FMA-issue cycles); nothing left for the compiler to sink
// expensively. Floor: 131k cyc/SIMD FMA issue = 54.6us; target 70-95us.

#pragma clang fp contract(off)

#define VQ_D 64
#define VQ_K 512
#define VQ_HW 4096
#define VQ_N 131072
#define XS_STRIDE 68  // 64 + 4 pad; rows 272B (16B-aligned for b128 reads)

__global__ void vq_sqe_kernel(const float* __restrict__ cb,
                              float* __restrict__ sqe) {
    const int k = threadIdx.x;  // 512 threads, one block
    float s = cb[k] * cb[k];    // d = 0 (square rounded, then added: no fma)
    for (int d = 1; d < VQ_D; ++d) {
        const float v = cb[d * VQ_K + k];
        const float sq = v * v;  // contract(off): rounds the square
        s = s + sq;              // then rounds the add (numpy axis-0 reduce)
    }
    sqe[k] = s;
}

__global__ __launch_bounds__(256, 2) void vq_main_kernel(
    const float* __restrict__ enc, const float* __restrict__ cb,
    const float* __restrict__ sqe, float* __restrict__ out) {
    __shared__ float xs[256 * XS_STRIDE];  // 69632 B -> 2 blocks/CU

    const int tid = threadIdx.x;
    const int pos0 = blockIdx.x * 256;     // grid divides N exactly
    const int b = pos0 >> 12;              // block lies within one b (256|4096)
    const int r0 = pos0 & (VQ_HW - 1);
    const float* ebase = enc + (size_t)b * (VQ_D * VQ_HW) + r0;

    // Stage this block's 256 positions into LDS, xs[p][d].
    // Global side: lane index = p -> fully coalesced per-d 1KB segments.
#pragma unroll 8
    for (int d = 0; d < VQ_D; ++d)
        xs[tid * XS_STRIDE + d] = ebase[(size_t)d * VQ_HW + tid];
    __syncthreads();

    const float* xp = &xs[tid * XS_STRIDE];

    // sq_x: exact emulation of numpy pairwise_sum over fl(x*x), n=64.
    float pr[8];
#pragma unroll
    for (int j = 0; j < 8; ++j) pr[j] = xp[j] * xp[j];
#pragma unroll
    for (int i = 8; i < VQ_D; i += 8) {
#pragma unroll
        for (int j = 0; j < 8; ++j) {
            const float sq = xp[i + j] * xp[i + j];  // rounded square
            pr[j] = pr[j] + sq;                      // rounded add
        }
    }
    const float sqx = ((pr[0] + pr[1]) + (pr[2] + pr[3])) +
                      ((pr[4] + pr[5]) + (pr[6] + pr[7]));

    float best = 3.402823466e38f;
    int bestk = 0;

    // K tiled by 16; kt is loop-uniform (NOT thread-derived) so cb/sqe
    // indices are provably uniform -> s_load scalar path (SMEM broadcast).
    for (int kt = 0; kt < VQ_K; kt += 16) {
        float acc[16];
#pragma unroll
        for (int j = 0; j < 16; ++j) acc[j] = 0.f;
#pragma unroll
        for (int d0 = 0; d0 < VQ_D; d0 += 4) {
            // One ds_read_b128 of this thread's x row feeds 64 FMAs.
            const float4 xv = *reinterpret_cast<const float4*>(&xp[d0]);
            const float xa[4] = {xv.x, xv.y, xv.z, xv.w};
#pragma unroll
            for (int dd = 0; dd < 4; ++dd) {
#pragma unroll
                for (int j = 0; j < 16; ++j)  // ascending-d FMA chain == sgemm
                    acc[j] = fmaf(xa[dd], cb[(d0 + dd) * VQ_K + kt + j], acc[j]);
            }
        }
#pragma unroll
        for (int j = 0; j < 16; ++j) {
            const float m2 = 2.0f * acc[j];        // exact (power of 2)
            const float tmp = sqx - m2;            // rounds: fl(sq_x - 2M)
            const float dist = tmp + sqe[kt + j];  // rounds: + sq_e
            if (dist < best) {  // strict '<': first (lowest) index on ties
                best = dist;
                bestk = kt + j;
            }
        }
    }

    // Gather winning codebook column, store strided (coalesced across lanes).
    float* op = out + (size_t)b * (VQ_D * VQ_HW) + r0 + tid;
#pragma unroll 8
    for (int d = 0; d < VQ_D; ++d)
        op[(size_t)d * VQ_HW] = cb[d * VQ_K + bestk];
}

extern "C" void kernel_launch(void* const* d_in, const int* in_sizes, int n_in,
                              void* d_out, int out_size, void* d_ws, size_t ws_size,
                              hipStream_t stream) {
    const float* enc = (const float*)d_in[0];  // [32,64,64,64]
    const float* cb  = (const float*)d_in[1];  // [64,512]
    float* out = (float*)d_out;
    float* sqe = (float*)d_ws;  // 512 floats

    vq_sqe_kernel<<<1, VQ_K, 0, stream>>>(cb, sqe);
    vq_main_kernel<<<VQ_N / 256, 256, 0, stream>>>(enc, cb, sqe, out);
}